// Round 1
// baseline (122.243 us; speedup 1.0000x reference)
//
#include <hip/hip_runtime.h>
#include <math.h>

#define TOPK_K 10
#define EPS_F 1e-9f
#define IOU_EPS_F 1e-7f

struct Iou6 { float ov; float ov6; };

// NOTE: contract(off) so both kernels compute bit-identical IoU/align values.
// The score==1 test compares k_assign's align against k_topk's stored max;
// any cross-kernel FMA-contraction difference would break exact equality.
__device__ __forceinline__ Iou6 iou_pow6(float px1, float py1, float px2, float py2,
                                         float gx1, float gy1, float gx2, float gy2) {
#pragma clang fp contract(off)
  float ix1 = fmaxf(px1, gx1);
  float iy1 = fmaxf(py1, gy1);
  float ix2 = fminf(px2, gx2);
  float iy2 = fminf(py2, gy2);
  float dw = fmaxf(ix2 - ix1, 0.0f);
  float dh = fmaxf(iy2 - iy1, 0.0f);
  float inter = dw * dh;
  float a1 = (px2 - px1) * (py2 - py1);
  float a2 = (gx2 - gx1) * (gy2 - gy1);
  float den = a1 + a2 - inter + IOU_EPS_F;
  float iou = inter / den;
  float ov = fmaxf(iou, 0.0f);
  float ov2 = ov * ov;
  Iou6 r; r.ov = ov; r.ov6 = ov2 * ov2 * ov2;
  return r;
}

__device__ __forceinline__ float sigmoid_f(float x) {
#pragma clang fp contract(off)
  return 1.0f / (1.0f + expf(-x));
}

// ---------------------------------------------------------------------------
// Kernel 1: per (b,m) stable top-10 of align over N anchors + row max.
// Stable semantics = lax.top_k: sort by (val desc, idx asc).
// ---------------------------------------------------------------------------
__launch_bounds__(256)
__global__ void k_topk(const float* __restrict__ pd_scores,
                       const float* __restrict__ pd_bboxes,
                       const int*   __restrict__ gt_labels,
                       const float* __restrict__ gt_bboxes,
                       const float* __restrict__ mask_gt,
                       int B, int N, int M, int C,
                       int*   __restrict__ topk_idx,   // [B*M*10]
                       float* __restrict__ maxv_out)   // [B*M]
{
  const int m = blockIdx.x, b = blockIdx.y;
  const int tid = threadIdx.x;
  const int bm = b * M + m;

  __shared__ float redv[4];
  __shared__ int   redi[4];

  const float mg = mask_gt[bm];
  if (mg == 0.0f) {
    // align row all-zero -> keep=false, max=0
    if (tid < TOPK_K) topk_idx[bm * TOPK_K + tid] = -1;
    if (tid == 0) maxv_out[bm] = 0.0f;
    return;
  }

  const float4 g = *(const float4*)(gt_bboxes + (size_t)bm * 4);
  int gl = gt_labels[bm];
  gl = min(max(gl, 0), C - 1);
  const float* __restrict__ srow = pd_scores + (size_t)b * N * C;

  // register ladder: lv sorted descending, ties keep earlier index
  float lv[TOPK_K]; int li[TOPK_K];
#pragma unroll
  for (int j = 0; j < TOPK_K; ++j) { lv[j] = -1.0f; li[j] = -1; }

  for (int n = tid; n < N; n += 256) {
    const float4 p = *(const float4*)(pd_bboxes + ((size_t)b * N + n) * 4);
    Iou6 io = iou_pow6(p.x, p.y, p.z, p.w, g.x, g.y, g.z, g.w);
    // align = sigmoid(score)*ov^6 < ov^6 (sig<1), so ov6 <= lv[9] => skip is sound
    if (io.ov6 > lv[TOPK_K - 1]) {
      float a;
      if (io.ov6 == 0.0f) {
        a = 0.0f;                       // sig*0 == 0 exactly: skip the gather
      } else {
        float s = srow[(size_t)n * C + gl];
        a = sigmoid_f(s) * io.ov6;      // ALPHA=1, mg==1 here
      }
      if (a > lv[TOPK_K - 1]) {
        // unrolled stable insertion (all static indices -> stays in VGPRs)
#pragma unroll
        for (int j = TOPK_K - 1; j >= 0; --j) {
          bool shift = (j >= 1) && (a > lv[j - 1]);
          if (shift)            { lv[j] = lv[j - 1]; li[j] = li[j - 1]; }
          else if (a > lv[j])   { lv[j] = a;         li[j] = n; }
        }
      }
    }
  }

  // merge 256 ladders: 10 rounds of block-argmax over ladder heads (lv[0]).
  // pop = static unrolled shift (avoids runtime-indexed register arrays).
  const int lane = tid & 63;
  const int wid  = tid >> 6;
  bool keep = false;
  for (int r = 0; r < TOPK_K; ++r) {
    float v = lv[0]; int ii = li[0];
#pragma unroll
    for (int off = 32; off > 0; off >>= 1) {
      float vv = __shfl_xor(v, off);
      int   jj = __shfl_xor(ii, off);
      if (vv > v || (vv == v && (unsigned)jj < (unsigned)ii)) { v = vv; ii = jj; }
    }
    if (lane == 0) { redv[wid] = v; redi[wid] = ii; }
    __syncthreads();
    float v4 = redv[0]; int i4 = redi[0];
#pragma unroll
    for (int w = 1; w < 4; ++w) {
      float vv = redv[w]; int jj = redi[w];
      if (vv > v4 || (vv == v4 && (unsigned)jj < (unsigned)i4)) { v4 = vv; i4 = jj; }
    }
    if (r == 0) {
      float maxv = fmaxf(v4, 0.0f);
      keep = maxv > EPS_F;              // keep = topk_vals.max > EPS
      if (tid == 0) maxv_out[bm] = maxv;
    }
    if (tid == 0) topk_idx[bm * TOPK_K + r] = keep ? i4 : -1;
    if (li[0] == i4 && lv[0] == v4) {   // unique owner pops (indices unique)
#pragma unroll
      for (int j = 0; j < TOPK_K - 1; ++j) { lv[j] = lv[j + 1]; li[j] = li[j + 1]; }
      lv[TOPK_K - 1] = -2.0f; li[TOPK_K - 1] = -1;
    }
    __syncthreads();
  }
}

// ---------------------------------------------------------------------------
// Kernel 2: per-anchor assignment + all outputs.
// ---------------------------------------------------------------------------
__launch_bounds__(256)
__global__ void k_assign(const float* __restrict__ pd_scores,
                         const float* __restrict__ pd_bboxes,
                         const float* __restrict__ anchors,
                         const int*   __restrict__ gt_labels,
                         const float* __restrict__ gt_bboxes,
                         const float* __restrict__ mask_gt,
                         const int*   __restrict__ topk_idx,
                         const float* __restrict__ maxv_in,
                         int B, int N, int M, int C,
                         float* __restrict__ out)
{
  const int b = blockIdx.y;
  const int chunk0 = blockIdx.x * 256;
  const int tid = threadIdx.x;

  __shared__ float4   sgt[128];
  __shared__ int      sgl[128];
  __shared__ float    smg[128];
  __shared__ float    smpg[128];
  __shared__ float    spre[128];
  __shared__ unsigned sbm[128 * 8];   // membership bitmap: 256 anchors per m
  __shared__ int      slab[256];
  __shared__ float    ssv[256];

  if (tid < M) {
    sgt[tid] = *(const float4*)(gt_bboxes + (size_t)(b * M + tid) * 4);
    sgl[tid] = min(max(gt_labels[b * M + tid], 0), C - 1);
    smg[tid] = mask_gt[b * M + tid];
    float mv  = maxv_in[b * M + tid];
    float mpg = fmaxf(mv, EPS_F);       // clip(align.max, EPS)
    smpg[tid] = mpg;
    spre[tid] = mpg * 0.999999f;        // prefilter: q>=1 needs ov6 > mpg*(1-2^-23)
  }
  for (int i = tid; i < M * 8; i += 256) sbm[i] = 0u;
  __syncthreads();
  for (int t = tid; t < M * TOPK_K; t += 256) {
    int e = topk_idx[(size_t)(b * M) * TOPK_K + t];
    int rel = e - chunk0;
    if (rel >= 0 && rel < 256)
      atomicOr(&sbm[(t / TOPK_K) * 8 + (rel >> 5)], 1u << (rel & 31));
  }
  __syncthreads();

  float* __restrict__ out_bbox   = out;
  float* __restrict__ out_scores = out + (size_t)B * N * 4;
  float* __restrict__ out_fg     = out_scores + (size_t)B * N * C;
  float* __restrict__ out_tgt    = out_fg + (size_t)B * N;

  const int n = chunk0 + tid;
  int lab = 0; float sval = 0.0f;
  if (n < N) {
    const float4 p = *(const float4*)(pd_bboxes + ((size_t)b * N + n) * 4);
    const float ax = anchors[(size_t)n * 2];
    const float ay = anchors[(size_t)n * 2 + 1];
    const float* __restrict__ srow = pd_scores + ((size_t)b * N + n) * C;

    float ovmax = -1.0f; int ovarg = 0;
    int cnt = 0, firstpos = -1; bool one = false;

    for (int m = 0; m < M; ++m) {
      const float4 g = sgt[m];
      Iou6 io = iou_pow6(p.x, p.y, p.z, p.w, g.x, g.y, g.z, g.w);
      if (io.ov > ovmax) { ovmax = io.ov; ovarg = m; }   // first-occurrence argmax
      const float mgv = smg[m];
      const float d = fminf(fminf(ax - g.x, ay - g.y), fminf(g.z - ax, g.w - ay));
      const unsigned w = sbm[m * 8 + (tid >> 5)];
      const bool member = (w >> (tid & 31)) & 1u;
      if ((d > EPS_F) && member && (mgv > 0.0f)) {
        cnt++;
        if (firstpos < 0) firstpos = m;
      }
      // norm_align only matters via int32-truncation: test q >= 1.0 exactly,
      // prefiltered (align = sig*ov6 <= ov6) so the gather is rare.
      if ((mgv > 0.0f) && (io.ov6 >= spre[m])) {
        float a = sigmoid_f(srow[sgl[m]]) * io.ov6;      // identical expr to k_topk
        if (a / smpg[m] >= 1.0f) one = true;
      }
    }

    float fg; int tgt;
    if (cnt > 1)      { fg = 1.0f; tgt = ovarg; }        // where(multi, is_max, ...)
    else if (cnt == 1){ fg = 1.0f; tgt = firstpos; }
    else              { fg = 0.0f; tgt = 0; }            // argmax of all-zero row = 0

    lab  = sgl[tgt];
    sval = (fg > 0.0f && one) ? 1.0f : 0.0f;

    *(float4*)(out_bbox + ((size_t)b * N + n) * 4) = sgt[tgt];
    out_fg[(size_t)b * N + n]  = fg;
    out_tgt[(size_t)b * N + n] = (float)tgt;
  }
  slab[tid] = lab; ssv[tid] = sval;
  __syncthreads();

  // cooperative coalesced write of the (rows x C) score tile
  const int rows = min(256, N - chunk0);
  const int c4n = C >> 2;
  float4* __restrict__ os4 = (float4*)(out_scores + ((size_t)b * N + chunk0) * C);
  const int tot = rows * c4n;
  for (int i = tid; i < tot; i += 256) {
    int row = i / c4n;
    int c0 = (i - row * c4n) * 4;
    int lr = slab[row]; float v = ssv[row];
    float4 o;
    o.x = (c0     == lr) ? v : 0.0f;
    o.y = (c0 + 1 == lr) ? v : 0.0f;
    o.z = (c0 + 2 == lr) ? v : 0.0f;
    o.w = (c0 + 3 == lr) ? v : 0.0f;
    os4[i] = o;
  }
}

extern "C" void kernel_launch(void* const* d_in, const int* in_sizes, int n_in,
                              void* d_out, int out_size, void* d_ws, size_t ws_size,
                              hipStream_t stream) {
  const float* pd_scores = (const float*)d_in[0];
  const float* pd_bboxes = (const float*)d_in[1];
  const float* anchors   = (const float*)d_in[2];
  const int*   gt_labels = (const int*)d_in[3];
  const float* gt_bboxes = (const float*)d_in[4];
  const float* mask_gt   = (const float*)d_in[5];

  const int N = in_sizes[2] / 2;               // anchor_points (N,2)
  const int B = in_sizes[1] / (N * 4);         // pd_bboxes (B,N,4)
  const int M = in_sizes[3] / B;               // gt_labels (B,M,1)
  const int C = in_sizes[0] / (B * N);         // pd_scores (B,N,C)

  int*   topk = (int*)d_ws;                                   // B*M*10 ints
  float* maxv = (float*)((char*)d_ws + (size_t)B * M * TOPK_K * sizeof(int));

  dim3 g1(M, B);
  k_topk<<<g1, 256, 0, stream>>>(pd_scores, pd_bboxes, gt_labels, gt_bboxes,
                                 mask_gt, B, N, M, C, topk, maxv);

  dim3 g2((N + 255) / 256, B);
  k_assign<<<g2, 256, 0, stream>>>(pd_scores, pd_bboxes, anchors, gt_labels,
                                   gt_bboxes, mask_gt, topk, maxv,
                                   B, N, M, C, (float*)d_out);
}